// Round 5
// baseline (488.476 us; speedup 1.0000x reference)
//
#include <hip/hip_runtime.h>
#include <stdint.h>

#define D   512      // embedding dim; also bytes per row in fp8
#define BM  128
#define BN  128

typedef __attribute__((ext_vector_type(4))) float f32x4;   // MFMA accumulator
typedef __attribute__((ext_vector_type(8))) int  i32x8;    // 32B MX A/B fragment

union frag32 { i32x8 v; uint4 q[2]; };

__device__ __forceinline__ void gld_lds16(const void* g, void* l) {
  __builtin_amdgcn_global_load_lds(
      (const __attribute__((address_space(1))) void*)g,
      (__attribute__((address_space(3))) void*)l, 16, 0, 0);
}

// One wave per row: load 512 fp32, shuffle-reduce sumsq, write 512 fp8 (e4m3, x16).
// Pre-scale by 16 keeps values in e4m3 normal range; undone by scale/256 in the
// GEMM epilogue (exact, power of 2). Block 0 thread 0 zeroes the output accumulator.
__global__ void norm_kernel(const float* __restrict__ img,
                            const float* __restrict__ prof,
                            uint8_t* __restrict__ outA,
                            uint8_t* __restrict__ outB,
                            float* __restrict__ out, int n) {
  if (blockIdx.x == 0 && threadIdx.x == 0) out[0] = 0.0f;
  int wave = threadIdx.x >> 6, lane = threadIdx.x & 63;
  int gw = blockIdx.x * 4 + wave;
  if (gw >= 2 * n) return;
  const float* src;
  uint8_t* dst;
  if (gw < n) { src = img  + (size_t)gw * D; dst = outA + (size_t)gw * D; }
  else        { src = prof + (size_t)(gw - n) * D; dst = outB + (size_t)(gw - n) * D; }

  const float4* s4 = (const float4*)src + lane * 2;
  float4 a = s4[0], b = s4[1];
  float ss = a.x*a.x + a.y*a.y + a.z*a.z + a.w*a.w
           + b.x*b.x + b.y*b.y + b.z*b.z + b.w*b.w;
#pragma unroll
  for (int m = 1; m < 64; m <<= 1) ss += __shfl_xor(ss, m, 64);
  float inv = 16.0f / fmaxf(sqrtf(ss), 1e-12f);

  // Within-pair byte order of cvt_pk cancels between A and B (same K-permutation).
  uint32_t lo = __builtin_amdgcn_cvt_pk_fp8_f32(a.x*inv, a.y*inv, 0,  false);
  lo          = __builtin_amdgcn_cvt_pk_fp8_f32(a.z*inv, a.w*inv, lo, true);
  uint32_t hi = __builtin_amdgcn_cvt_pk_fp8_f32(b.x*inv, b.y*inv, 0,  false);
  hi          = __builtin_amdgcn_cvt_pk_fp8_f32(b.z*inv, b.w*inv, hi, true);
  uint2 pk; pk.x = lo; pk.y = hi;
  *(uint2*)(dst + lane * 8) = pk;
}

// softplus(x)=log(1+e^x). Here |x|>=7.28 always => series corr = t - t^2/2 exact
// to ~1e-7. Precise branch kept for safety; wave-coherent, never taken.
__device__ __forceinline__ float softplus_f(float x) {
  float ax = fabsf(x);
  float t = __expf(-ax);
  float corr;
  if (__builtin_expect(ax < 5.0f, 0)) corr = __logf(1.0f + t);
  else                                corr = t - 0.5f * t * t;
  return fmaxf(x, 0.0f) + corr;
}

// C = A(img) x B(prof)^T in fp8 e4m3 via MX MFMA 16x16x128, unit scales (e8m0=127).
//
// BARRIER-FREE K-LOOP: all of B's tile (128 rows x 512 B = 64 KB) is staged into
// LDS once (one barrier), then the K-loop runs with ZERO barriers — A fragments
// are loaded straight from global (strip-resident L2) as 2x dwordx4 per tile, so
// the compiler can hoist them across the whole loop with fine-grained vmcnt
// (the AITER-style pipelining the 2-barrier-per-iter structure cannot express).
//
// B LDS swizzle: row r holds 32 chunks of 16 B; LDS slot s stores global chunk
// j = (s&~7)|((s&7)^(r&7)). Staging stays wave-uniform-base + lane*16 (the
// global_load_lds contract); frag ds_read_b128 lands at the structural minimum
// 8 addresses/bank. Read slot for (r, j): s = (j&~7)|((j&7)^(r&7)).
//
// XCD strip mapping (r2): each XCD owns a 16-block-row strip, sweeps columns;
// A-strip stays resident in its 4 MB L2, B streams with 16x reuse.
__global__ __launch_bounds__(256, 2) void siglip_gemm(
    const uint8_t* __restrict__ A, const uint8_t* __restrict__ B,
    const float* __restrict__ scale_p, const float* __restrict__ bias_p,
    const int* __restrict__ buckets_p, float* __restrict__ out, int n) {
  __shared__ __align__(16) uint8_t sB[BN * D];   // 64 KB
  __shared__ float red[4];

  int tid = threadIdx.x;
  int lane = tid & 63, wave = tid >> 6;
  int quad = lane >> 4, l16 = lane & 15;

  int nb = n / BM;
  int bm, bn;
  int nstrips = nb >> 4;
  if ((nb & 15) == 0 && nstrips > 0) {
    int strip = blockIdx.x % nstrips;    // == XCD id under round-robin dispatch
    int idx   = blockIdx.x / nstrips;
    bm = strip * 16 + (idx & 15);
    bn = idx >> 4;
  } else {
    bm = blockIdx.x % nb;
    bn = blockIdx.x / nb;
  }

  int rowB = bm * BM, colB = bn * BN;
  const uint8_t* Ag = A + (size_t)rowB * D;
  const uint8_t* Bg = B + (size_t)colB * D;

  float scale = __expf(scale_p[0]) * (1.0f / 256.0f);   // undo x16 quant pre-scale
  float bias  = bias_p[0];
  int buckets = buckets_p[0];

  int wm = (wave >> 1) * 64, wn = (wave & 1) * 64;

  // ---- stage ALL of B: 4096 16B-chunks, 16 per thread, one barrier ----
#pragma unroll
  for (int p = 0; p < 16; p++) {
    int c = p * 256 + tid;
    int r = c >> 5, s = c & 31;
    int j = (s & ~7) | ((s & 7) ^ (r & 7));
    gld_lds16(Bg + (size_t)r * D + j * 16, &sB[c * 16]);
  }
  __syncthreads();

  f32x4 acc[4][4];
#pragma unroll
  for (int i = 0; i < 4; i++)
#pragma unroll
    for (int j = 0; j < 4; j++) { acc[i][j].x = 0.f; acc[i][j].y = 0.f; acc[i][j].z = 0.f; acc[i][j].w = 0.f; }

  // ---- barrier-free K loop: 4 chunks of k=128 ----
#pragma unroll
  for (int kc = 0; kc < 4; kc++) {
    int kbase = kc * 128 + quad * 32;     // this lane's 32 contiguous k-bytes
    frag32 af[4], bf[4];
#pragma unroll
    for (int t = 0; t < 4; t++) {
      // A direct from global: row = wm + t*16 + l16, 32 contiguous bytes
      const uint8_t* ap = Ag + (size_t)(wm + t * 16 + l16) * D + kbase;
      af[t].q[0] = *(const uint4*)ap;
      af[t].q[1] = *(const uint4*)(ap + 16);
      // B from LDS (swizzled)
      int rb = wn + t * 16 + l16, e = rb & 7;
      int j0 = 2 * quad, j1 = 2 * quad + 1;      // chunk-in-128B indices
      const uint8_t* bp = &sB[rb * D + kc * 128];
      bf[t].q[0] = *(const uint4*)(bp + ((j0 ^ e) << 4));
      bf[t].q[1] = *(const uint4*)(bp + ((j1 ^ e) << 4));
    }
#pragma unroll
    for (int tm = 0; tm < 4; tm++)
#pragma unroll
      for (int tn = 0; tn < 4; tn++)
        acc[tm][tn] = __builtin_amdgcn_mfma_scale_f32_16x16x128_f8f6f4(
            af[tm].v, bf[tn].v, acc[tm][tn],
            0, 0,            // cbsz=0 (A=fp8 e4m3), blgp=0 (B=fp8 e4m3)
            0, 127,          // scale_src0: e8m0 127 -> x1.0
            0, 127);         // scale_src1: e8m0 127 -> x1.0
  }

  // ---- fused loss epilogue ----
  // C/D layout: col = lane&15, row = quad*4 + reg (shape-determined, m121/m127)
  float local = 0.0f;
  if (buckets == 1) {
#pragma unroll
    for (int tm = 0; tm < 4; tm++)
#pragma unroll
      for (int tn = 0; tn < 4; tn++)
#pragma unroll
        for (int e = 0; e < 4; e++) {
          int r = rowB + wm + tm * 16 + quad * 4 + e;
          int c = colB + wn + tn * 16 + l16;
          float v = acc[tm][tn][e] * scale + bias;
          float x = (r == c) ? -v : v;     // contribution = softplus(-z)
          local += softplus_f(x);
        }
  } else {
    unsigned bs = (unsigned)n / (unsigned)buckets;
#pragma unroll
    for (int tm = 0; tm < 4; tm++)
#pragma unroll
      for (int tn = 0; tn < 4; tn++)
#pragma unroll
        for (int e = 0; e < 4; e++) {
          int r = rowB + wm + tm * 16 + quad * 4 + e;
          int c = colB + wn + tn * 16 + l16;
          if ((unsigned)r / bs != (unsigned)c / bs) continue;
          float v = acc[tm][tn][e] * scale + bias;
          float x = (r == c) ? -v : v;
          local += softplus_f(x);
        }
  }

#pragma unroll
  for (int m = 1; m < 64; m <<= 1) local += __shfl_xor(local, m, 64);
  if (lane == 0) red[wave] = local;
  __syncthreads();
  if (tid == 0) {
    float bsum = red[0] + red[1] + red[2] + red[3];
    atomicAdd(out, bsum * (1.0f / (float)n));
  }
}

extern "C" void kernel_launch(void* const* d_in, const int* in_sizes, int n_in,
                              void* d_out, int out_size, void* d_ws, size_t ws_size,
                              hipStream_t stream) {
  const float* img  = (const float*)d_in[0];
  const float* prof = (const float*)d_in[1];
  const float* lsc  = (const float*)d_in[2];
  const float* bia  = (const float*)d_in[3];
  const int*   bkt  = (const int*)d_in[4];
  float* out = (float*)d_out;

  int n = in_sizes[0] / D;                 // 16384
  uint8_t* wsA = (uint8_t*)d_ws;           // n*512 fp8
  uint8_t* wsB = wsA + (size_t)n * D;      // n*512 fp8

  norm_kernel<<<(2 * n + 3) / 4, 256, 0, stream>>>(img, prof, wsA, wsB, out, n);
  int nb = n / BM;
  siglip_gemm<<<nb * nb, 256, 0, stream>>>(wsA, wsB, lsc, bia, bkt, out, n);
}

// Round 6
// 367.369 us; speedup vs baseline: 1.3297x; 1.3297x over previous
//
#include <hip/hip_runtime.h>
#include <stdint.h>

#define D   512      // embedding dim; also bytes per row in fp8
#define BM  128
#define BN  128

typedef __attribute__((ext_vector_type(4))) float f32x4;   // MFMA accumulator
typedef __attribute__((ext_vector_type(8))) int  i32x8;    // 32B MX A/B fragment

union frag32 { i32x8 v; uint4 q[2]; };

__device__ __forceinline__ void gld_lds16(const void* g, void* l) {
  __builtin_amdgcn_global_load_lds(
      (const __attribute__((address_space(1))) void*)g,
      (__attribute__((address_space(3))) void*)l, 16, 0, 0);
}

// One wave per row: load 512 fp32, shuffle-reduce sumsq, write 512 fp8 (e4m3, x16).
// Pre-scale by 16 keeps values in e4m3 normal range; undone by scale/256 in the
// GEMM epilogue (exact, power of 2). Block 0 thread 0 zeroes the output accumulator.
//
// A (img) is written PRE-PACKED in MFMA A-fragment order so the GEMM can read
// fragments with fully-coalesced global loads (r5 post-mortem: direct row-major
// frag reads are a 512B-stride gather — 16 lines/quad — and killed the kernel):
//   P[row>>4][kc=k>>7][quad=(k>>5)&3][m=row&15][b=k&31]
//   byte k of row r  ->  (r>>4)*8192 + (k>>7)*2048 + ((k>>5)&3)*512 + (r&15)*32 + (k&31)
// Lane l holds k-bytes 8l..8l+7 -> kc=l>>4, quad=(l>>2)&3, b=(l&3)*8.
// B (prof) stays row-major (global_load_lds stages rows contiguously).
__global__ void norm_kernel(const float* __restrict__ img,
                            const float* __restrict__ prof,
                            uint8_t* __restrict__ outA,
                            uint8_t* __restrict__ outB,
                            float* __restrict__ out, int n) {
  if (blockIdx.x == 0 && threadIdx.x == 0) out[0] = 0.0f;
  int wave = threadIdx.x >> 6, lane = threadIdx.x & 63;
  int gw = blockIdx.x * 4 + wave;
  if (gw >= 2 * n) return;
  bool isA = gw < n;
  int row = isA ? gw : gw - n;
  const float* src = (isA ? img : prof) + (size_t)row * D;

  const float4* s4 = (const float4*)src + lane * 2;
  float4 a = s4[0], b = s4[1];
  float ss = a.x*a.x + a.y*a.y + a.z*a.z + a.w*a.w
           + b.x*b.x + b.y*b.y + b.z*b.z + b.w*b.w;
#pragma unroll
  for (int m = 1; m < 64; m <<= 1) ss += __shfl_xor(ss, m, 64);
  float inv = 16.0f / fmaxf(sqrtf(ss), 1e-12f);

  // Within-pair byte order of cvt_pk cancels between A and B (same K-permutation).
  uint32_t lo = __builtin_amdgcn_cvt_pk_fp8_f32(a.x*inv, a.y*inv, 0,  false);
  lo          = __builtin_amdgcn_cvt_pk_fp8_f32(a.z*inv, a.w*inv, lo, true);
  uint32_t hi = __builtin_amdgcn_cvt_pk_fp8_f32(b.x*inv, b.y*inv, 0,  false);
  hi          = __builtin_amdgcn_cvt_pk_fp8_f32(b.z*inv, b.w*inv, hi, true);
  uint2 pk; pk.x = lo; pk.y = hi;

  if (isA) {
    size_t off = (size_t)(row >> 4) * 8192 + (size_t)(lane >> 4) * 2048
               + (size_t)((lane >> 2) & 3) * 512 + (size_t)(row & 15) * 32
               + (size_t)(lane & 3) * 8;
    *(uint2*)(outA + off) = pk;          // 4-lane 32B clusters; A write = 8 MB total
  } else {
    *(uint2*)(outB + (size_t)row * D + lane * 8) = pk;
  }
}

// softplus(x)=log(1+e^x). Here |x|>=7.28 always => series corr = t - t^2/2 exact
// to ~1e-7. Precise branch kept for safety; wave-coherent, never taken.
__device__ __forceinline__ float softplus_f(float x) {
  float ax = fabsf(x);
  float t = __expf(-ax);
  float corr;
  if (__builtin_expect(ax < 5.0f, 0)) corr = __logf(1.0f + t);
  else                                corr = t - 0.5f * t * t;
  return fmaxf(x, 0.0f) + corr;
}

// C = A(img) x B(prof)^T in fp8 e4m3 via MX MFMA 16x16x128, unit scales (e8m0=127).
//
// BARRIER-FREE K-LOOP (r5 skeleton, r6 A-path fix): all of B's tile (64 KB) is
// staged into LDS once (one barrier), then the K-loop runs with zero barriers.
// A fragments come straight from global in PACKED layout (see norm_kernel):
// per (t,kc) a wave reads 2 KB contiguous (lane*32) from the strip-resident L2 —
// the compiler is free to hoist/pipeline these with fine-grained vmcnt.
//
// B LDS swizzle: row r holds 32 chunks of 16 B; LDS slot s stores global chunk
// j = (s&~7)|((s&7)^(r&7)). Staging keeps the wave-uniform-base + lane*16
// global_load_lds contract; frag ds_read_b128 = structural-minimum 8 addr/bank.
//
// XCD strip mapping (r2): each XCD owns a 16-block-row strip, sweeps columns;
// A-strip stays resident in its 4 MB L2, B streams with 16x reuse.
__global__ __launch_bounds__(256, 2) void siglip_gemm(
    const uint8_t* __restrict__ A, const uint8_t* __restrict__ B,
    const float* __restrict__ scale_p, const float* __restrict__ bias_p,
    const int* __restrict__ buckets_p, float* __restrict__ out, int n) {
  __shared__ __align__(16) uint8_t sB[BN * D];   // 64 KB
  __shared__ float red[4];

  int tid = threadIdx.x;
  int lane = tid & 63, wave = tid >> 6;
  int quad = lane >> 4, l16 = lane & 15;

  int nb = n / BM;
  int bm, bn;
  int nstrips = nb >> 4;
  if ((nb & 15) == 0 && nstrips > 0) {
    int strip = blockIdx.x % nstrips;    // == XCD id under round-robin dispatch
    int idx   = blockIdx.x / nstrips;
    bm = strip * 16 + (idx & 15);
    bn = idx >> 4;
  } else {
    bm = blockIdx.x % nb;
    bn = blockIdx.x / nb;
  }

  int rowB = bm * BM, colB = bn * BN;
  const uint8_t* Bg = B + (size_t)colB * D;

  float scale = __expf(scale_p[0]) * (1.0f / 256.0f);   // undo x16 quant pre-scale
  float bias  = bias_p[0];
  int buckets = buckets_p[0];

  int wm = (wave >> 1) * 64, wn = (wave & 1) * 64;
  // packed-A base for this wave's 64 rows (rowB+wm is a multiple of 16)
  const uint8_t* Apk = A + (size_t)(rowB + wm) * D + (size_t)lane * 32;

  // ---- stage ALL of B: 4096 16B-chunks, 16 per thread, one barrier ----
#pragma unroll
  for (int p = 0; p < 16; p++) {
    int c = p * 256 + tid;
    int r = c >> 5, s = c & 31;
    int j = (s & ~7) | ((s & 7) ^ (r & 7));
    gld_lds16(Bg + (size_t)r * D + j * 16, &sB[c * 16]);
  }
  __syncthreads();

  f32x4 acc[4][4];
#pragma unroll
  for (int i = 0; i < 4; i++)
#pragma unroll
    for (int j = 0; j < 4; j++) { acc[i][j].x = 0.f; acc[i][j].y = 0.f; acc[i][j].z = 0.f; acc[i][j].w = 0.f; }

  // ---- barrier-free K loop: 4 chunks of k=128 ----
#pragma unroll
  for (int kc = 0; kc < 4; kc++) {
    frag32 af[4], bf[4];
#pragma unroll
    for (int t = 0; t < 4; t++) {
      // A: packed fragment, fully coalesced 2 KB wave-read from L2
      af[t].v = *(const i32x8*)(Apk + (size_t)t * 8192 + (size_t)kc * 2048);
      // B: LDS, swizzled b128 pair
      int rb = wn + t * 16 + l16, e = rb & 7;
      int j0 = 2 * quad, j1 = 2 * quad + 1;      // 16B chunk-in-128B indices
      const uint8_t* bp = &sB[rb * D + kc * 128];
      bf[t].q[0] = *(const uint4*)(bp + ((j0 ^ e) << 4));
      bf[t].q[1] = *(const uint4*)(bp + ((j1 ^ e) << 4));
    }
#pragma unroll
    for (int tm = 0; tm < 4; tm++)
#pragma unroll
      for (int tn = 0; tn < 4; tn++)
        acc[tm][tn] = __builtin_amdgcn_mfma_scale_f32_16x16x128_f8f6f4(
            af[tm].v, bf[tn].v, acc[tm][tn],
            0, 0,            // cbsz=0 (A=fp8 e4m3), blgp=0 (B=fp8 e4m3)
            0, 127,          // scale_src0: e8m0 127 -> x1.0
            0, 127);         // scale_src1: e8m0 127 -> x1.0
  }

  // ---- fused loss epilogue ----
  // C/D layout: col = lane&15, row = quad*4 + reg (shape-determined, m121/m127)
  float local = 0.0f;
  if (buckets == 1) {
#pragma unroll
    for (int tm = 0; tm < 4; tm++)
#pragma unroll
      for (int tn = 0; tn < 4; tn++)
#pragma unroll
        for (int e = 0; e < 4; e++) {
          int r = rowB + wm + tm * 16 + quad * 4 + e;
          int c = colB + wn + tn * 16 + l16;
          float v = acc[tm][tn][e] * scale + bias;
          float x = (r == c) ? -v : v;     // contribution = softplus(-z)
          local += softplus_f(x);
        }
  } else {
    unsigned bs = (unsigned)n / (unsigned)buckets;
#pragma unroll
    for (int tm = 0; tm < 4; tm++)
#pragma unroll
      for (int tn = 0; tn < 4; tn++)
#pragma unroll
        for (int e = 0; e < 4; e++) {
          int r = rowB + wm + tm * 16 + quad * 4 + e;
          int c = colB + wn + tn * 16 + l16;
          if ((unsigned)r / bs != (unsigned)c / bs) continue;
          float v = acc[tm][tn][e] * scale + bias;
          float x = (r == c) ? -v : v;
          local += softplus_f(x);
        }
  }

#pragma unroll
  for (int m = 1; m < 64; m <<= 1) local += __shfl_xor(local, m, 64);
  if (lane == 0) red[wave] = local;
  __syncthreads();
  if (tid == 0) {
    float bsum = red[0] + red[1] + red[2] + red[3];
    atomicAdd(out, bsum * (1.0f / (float)n));
  }
}

extern "C" void kernel_launch(void* const* d_in, const int* in_sizes, int n_in,
                              void* d_out, int out_size, void* d_ws, size_t ws_size,
                              hipStream_t stream) {
  const float* img  = (const float*)d_in[0];
  const float* prof = (const float*)d_in[1];
  const float* lsc  = (const float*)d_in[2];
  const float* bia  = (const float*)d_in[3];
  const int*   bkt  = (const int*)d_in[4];
  float* out = (float*)d_out;

  int n = in_sizes[0] / D;                 // 16384
  uint8_t* wsA = (uint8_t*)d_ws;           // n*512 fp8, packed fragment layout
  uint8_t* wsB = wsA + (size_t)n * D;      // n*512 fp8, row-major

  norm_kernel<<<(2 * n + 3) / 4, 256, 0, stream>>>(img, prof, wsA, wsB, out, n);
  int nb = n / BM;
  siglip_gemm<<<nb * nb, 256, 0, stream>>>(wsA, wsB, lsc, bia, bkt, out, n);
}